// Round 16
// baseline (154.904 us; speedup 1.0000x reference)
//
#include <hip/hip_runtime.h>

typedef float f32x4 __attribute__((ext_vector_type(4)));
typedef float f32x16 __attribute__((ext_vector_type(16)));
typedef __bf16 bf16x4 __attribute__((ext_vector_type(4)));
typedef __bf16 bf16x8 __attribute__((ext_vector_type(8)));

constexpr int E = 1024;   // embed dim
constexpr int S = 2048;   // sequence length
constexpr int Bsz = 2;    // batch
constexpr int H = 16;     // heads
constexpr int Dh = 64;    // head dim
constexpr int M = Bsz * S; // 4096 rows
constexpr int E2 = 2048;  // ob row stride (two s-half partials, K-concat)

#define GLOAD_LDS16(g, l)                                                                 \
  __builtin_amdgcn_global_load_lds((const __attribute__((address_space(1))) void*)(g),    \
                                   (__attribute__((address_space(3))) void*)(l), 16, 0, 0)

__device__ __forceinline__ unsigned pk2(float a, float b) {
  union { __bf16 h[2]; unsigned u; } r;
  r.h[0] = (__bf16)a; r.h[1] = (__bf16)b;
  return r.u;
}

// ---------------------------------------------------------------------------
// fp32 -> bf16 convert pass (unchanged, verified).
// ---------------------------------------------------------------------------
__global__ __launch_bounds__(256) void convert_bf16(
    const float* __restrict__ q, const float* __restrict__ k,
    const float* __restrict__ v, const float* __restrict__ wq,
    const float* __restrict__ wk, const float* __restrict__ wv,
    const float* __restrict__ wo, __bf16* __restrict__ aq,
    __bf16* __restrict__ ak, __bf16* __restrict__ av,
    __bf16* __restrict__ wqkv, __bf16* __restrict__ wob) {
  const int id = blockIdx.y;
  const float* src;
  __bf16* dst;
  int n;
  float scale = 1.0f;
  switch (id) {
    case 0: src = q;  dst = aq;             n = M * E; break;
    case 1: src = k;  dst = ak;             n = M * E; break;
    case 2: src = v;  dst = av;             n = M * E; break;
    case 3: src = wq; dst = wqkv;           n = E * E; scale = -0.18033688f; break;
    case 4: src = wk; dst = wqkv + E * E;   n = E * E; break;
    case 5: src = wv; dst = wqkv + 2 * E * E; n = E * E; break;
    default: src = wo; dst = wob;           n = E * E; break;
  }
  const int stride = gridDim.x * 256 * 8;
  for (int i = (blockIdx.x * 256 + threadIdx.x) * 8; i < n; i += stride) {
    f32x4 a = *reinterpret_cast<const f32x4*>(&src[i]);
    f32x4 b = *reinterpret_cast<const f32x4*>(&src[i + 4]);
    bf16x8 o;
    o[0] = (__bf16)(a[0] * scale); o[1] = (__bf16)(a[1] * scale);
    o[2] = (__bf16)(a[2] * scale); o[3] = (__bf16)(a[3] * scale);
    o[4] = (__bf16)(b[0] * scale); o[5] = (__bf16)(b[1] * scale);
    o[6] = (__bf16)(b[2] * scale); o[7] = (__bf16)(b[3] * scale);
    *reinterpret_cast<bf16x8*>(&dst[i]) = o;
  }
}

// ---------------------------------------------------------------------------
// Merged QKV projection GEMM v5 (round-14 verified): exact m97 structure,
// 128x128 tile, BK=64, single 32 KB buffer, __syncthreads drain schedule,
// XCD-chunked m-major grid. pq/pk [B,H,S,D]; pvt [B,H,D,S] s bits-2<->3.
// ---------------------------------------------------------------------------
__global__ __launch_bounds__(256) void gemm_qkv(
    const __bf16* __restrict__ A0, const __bf16* __restrict__ A1,
    const __bf16* __restrict__ A2, const __bf16* __restrict__ Bw,
    __bf16* __restrict__ C0, __bf16* __restrict__ C1, __bf16* __restrict__ C2) {
  constexpr int NT  = 16;            // k-tiles of 64 (K=1024)
  constexpr int NTN = 24;            // 3072/128
  constexpr int NWG = 32 * NTN;      // 768
  constexpr int CPX = NWG / 8;       // 96

  __shared__ char smem[32768];       // A [128][64] 16KB | B [128][64] 16KB

  const int t    = threadIdx.x;
  const int lane = t & 63;
  const int wid  = t >> 6;
  const int wr   = (wid >> 1) * 64;
  const int wc   = (wid & 1) * 64;
  const int r16  = lane & 15;

  const int bid = blockIdx.x;
  const int fid = (bid & 7) * CPX + (bid >> 3);
  const int mt  = fid / NTN;
  const int nt  = fid % NTN;
  const int tm  = mt * 128;
  const int tn  = nt * 128;
  const int which = tn >> 10;

  const __bf16* Ab = which == 0 ? A0 : which == 1 ? A1 : A2;

  auto stage = [&](int kt) {
    const int k0 = kt * 64;
#pragma unroll
    for (int c = wid; c < 32; c += 4) {
      const bool isA = c < 16;
      const int cc   = isA ? c : c - 16;
      const int L    = cc * 1024 + lane * 16;   // byte offset in tile
      const int row  = L >> 7;                  // 128 B per row
      const int sw   = ((L >> 4) & 7) ^ (row & 7);
      const __bf16* src = isA ? &Ab[(size_t)(tm + row) * 1024 + k0 + sw * 8]
                              : &Bw[(size_t)(tn + row) * 1024 + k0 + sw * 8];
      GLOAD_LDS16(src, smem + c * 1024);
    }
  };

  f32x4 acc[4][4] = {};

  for (int kt = 0; kt < NT; ++kt) {
    __syncthreads();                 // prior tile's readers done
    stage(kt);
    __syncthreads();                 // full drain: tile kt staged

    const char* As = smem;
    const char* Bs = smem + 16384;

#pragma unroll
    for (int kc = 0; kc < 2; ++kc) {
      bf16x8 af[4], bfv[4];
#pragma unroll
      for (int mi = 0; mi < 4; ++mi) {
        int row = wr + mi * 16 + r16;
        int g   = (kc * 4 + (lane >> 4)) ^ (row & 7);
        af[mi] = *reinterpret_cast<const bf16x8*>(As + row * 128 + g * 16);
      }
#pragma unroll
      for (int ni = 0; ni < 4; ++ni) {
        int row = wc + ni * 16 + r16;
        int g   = (kc * 4 + (lane >> 4)) ^ (row & 7);
        bfv[ni] = *reinterpret_cast<const bf16x8*>(Bs + row * 128 + g * 16);
      }
      __builtin_amdgcn_s_setprio(1);
#pragma unroll
      for (int mi = 0; mi < 4; ++mi)
#pragma unroll
        for (int ni = 0; ni < 4; ++ni)
          acc[mi][ni] = __builtin_amdgcn_mfma_f32_16x16x32_bf16(af[mi], bfv[ni],
                                                                acc[mi][ni], 0, 0, 0);
      __builtin_amdgcn_s_setprio(0);
    }
  }

#pragma unroll
  for (int mi = 0; mi < 4; ++mi) {
#pragma unroll
    for (int ni = 0; ni < 4; ++ni) {
#pragma unroll
      for (int j = 0; j < 4; ++j) {
        float v = acc[mi][ni][j];
        int m = tm + wr + mi * 16 + ((lane >> 4) << 2) + j;
        int n = tn + wc + ni * 16 + r16;
        int nl = n & 1023;
        int b = m >> 11, s = m & 2047, h = nl >> 6, d = nl & 63;
        __bf16* Cout = which == 0 ? C0 : which == 1 ? C1 : C2;
        if (which < 2) {
          Cout[((size_t)(b * H + h) * S + s) * Dh + d] = (__bf16)v;
        } else {
          int ssw = (s & ~12) | ((s & 4) << 1) | ((s & 8) >> 1);
          Cout[((size_t)(b * H + h) * Dh + d) * S + ssw] = (__bf16)v;
        }
      }
    }
  }
}

// ---------------------------------------------------------------------------
// Final GEMM (round-7/9/14 verified): TM=64, counted-vmcnt dbuf, XCD-chunked
// grid. KS=2048 K-concat of the two s-half partials; B k-index wraps 1024.
// ---------------------------------------------------------------------------
template <int TM, int KS>
__global__ __launch_bounds__(256) void gemm_bf16nt(
    const __bf16* __restrict__ A0, const __bf16* __restrict__ Bw,
    float* __restrict__ C0) {
  static_assert(TM == 64, "vmcnt literal assumes TM=64 (6 chunks/wave)");
  constexpr int MI  = TM / 32;
  constexpr int NT  = KS / 64;
  constexpr int ACH = TM / 8;
  constexpr int NCH = ACH + 16;
  constexpr int NTN = 8;
  constexpr int NWG = NTN * (M / TM);
  constexpr int CPX = NWG / 8;

  __shared__ char smem[2][NCH * 1024];   // 48 KB total

  const int t    = threadIdx.x;
  const int lane = t & 63;
  const int wid  = t >> 6;
  const int wr   = (wid >> 1) * (TM / 2);
  const int wc   = (wid & 1) * 64;
  const int r16  = lane & 15;

  const int bid = blockIdx.x;
  const int fid = (bid & 7) * CPX + (bid >> 3);
  const int mt  = fid / NTN;
  const int nt  = fid % NTN;
  const int tm  = mt * TM;
  const int tn  = nt * 128;

  auto stage = [&](int kt, int buf) {
    const int k0  = kt * 64;
    const int k0b = k0 & 1023;
    char* dst = smem[buf];
#pragma unroll
    for (int c = wid; c < NCH; c += 4) {
      const bool isA = c < ACH;
      const int cc   = isA ? c : c - ACH;
      const int L    = cc * 1024 + lane * 16;
      const int row  = L >> 7;
      const int sw   = ((L >> 4) & 7) ^ (row & 7);
      const __bf16* src = isA ? &A0[(size_t)(tm + row) * KS + k0 + sw * 8]
                              : &Bw[(size_t)(tn + row) * 1024 + k0b + sw * 8];
      GLOAD_LDS16(src, dst + c * 1024);
    }
  };

  stage(0, 0);
  stage(1, 1);

  f32x4 acc[MI][4] = {};

  for (int kt = 0; kt < NT; ++kt) {
    const int buf = kt & 1;
    if (kt + 1 < NT) {
      asm volatile("s_waitcnt vmcnt(6)" ::: "memory");
    } else {
      asm volatile("s_waitcnt vmcnt(0)" ::: "memory");
    }
    __builtin_amdgcn_s_barrier();
    __builtin_amdgcn_sched_barrier(0);

    const __bf16* As = (const __bf16*)smem[buf];
    const __bf16* Bs = (const __bf16*)(smem[buf] + ACH * 1024);

#pragma unroll
    for (int kc = 0; kc < 2; ++kc) {
      bf16x8 af[MI], bfv[4];
#pragma unroll
      for (int mi = 0; mi < MI; ++mi) {
        int row = wr + mi * 16 + r16;
        int g   = (kc * 4 + (lane >> 4)) ^ (row & 7);
        af[mi] = *reinterpret_cast<const bf16x8*>(&As[row * 64 + g * 8]);
      }
#pragma unroll
      for (int ni = 0; ni < 4; ++ni) {
        int row = wc + ni * 16 + r16;
        int g   = (kc * 4 + (lane >> 4)) ^ (row & 7);
        bfv[ni] = *reinterpret_cast<const bf16x8*>(&Bs[row * 64 + g * 8]);
      }
      __builtin_amdgcn_s_setprio(1);
#pragma unroll
      for (int mi = 0; mi < MI; ++mi)
#pragma unroll
        for (int ni = 0; ni < 4; ++ni)
          acc[mi][ni] = __builtin_amdgcn_mfma_f32_16x16x32_bf16(af[mi], bfv[ni],
                                                                acc[mi][ni], 0, 0, 0);
      __builtin_amdgcn_s_setprio(0);
    }

    __builtin_amdgcn_sched_barrier(0);
    __builtin_amdgcn_s_barrier();
    if (kt + 2 < NT) stage(kt + 2, buf);
  }

#pragma unroll
  for (int mi = 0; mi < MI; ++mi) {
#pragma unroll
    for (int ni = 0; ni < 4; ++ni) {
#pragma unroll
      for (int j = 0; j < 4; ++j) {
        float v = acc[mi][ni][j];
        int m = tm + wr + mi * 16 + ((lane >> 4) << 2) + j;
        int n = tn + wc + ni * 16 + r16;
        C0[(size_t)m * E + n] = v;
      }
    }
  }
}

// ---------------------------------------------------------------------------
// Sigmoid attention v13 = v10's occupancy with v9's schedule: 1-wave blocks,
// 32 q-rows, s-half per block -> 4096 blocks = 4 waves/SIMD. 16 KB dbuf,
// depth-2 prefetch, counted vmcnt(8), zero barriers (v9's exact pipeline;
// v10's poison was single-buffer + per-iter vmcnt(0)). ZERO-C, in-register
// sigmoid, pre-permuted V. Partial O -> ss-th K-half of ob[M,2048].
// ---------------------------------------------------------------------------
__global__ __launch_bounds__(64, 4) void attn_sigmoid(const __bf16* __restrict__ Q,
                                                      const __bf16* __restrict__ K,
                                                      const __bf16* __restrict__ Vt,
                                                      __bf16* __restrict__ O) {
  __shared__ char smem[16384];   // [buf]: K tile 4KB (32s x 64d) + V tile 4KB

  const int t    = threadIdx.x;
  const int lane = t & 63;
  const int l31  = lane & 31;
  const int hh   = lane >> 5;
  const int qt   = blockIdx.x >> 1;
  const int ss   = blockIdx.x & 1;
  const int q0   = qt * 32;
  const int h    = blockIdx.y;
  const int b    = blockIdx.z;

  const __bf16* Qh = Q + (size_t)(b * H + h) * S * Dh;
  const __bf16* Kh = K + (size_t)(b * H + h) * S * Dh;
  const __bf16* Vh = Vt + (size_t)(b * H + h) * Dh * S;

  // per-lane swizzled source pointers (verified v6/v9 pattern)
  const __bf16* kSrc = Kh + (size_t)(ss * 1024 + (lane >> 3)) * Dh +
                       (((lane & 7) ^ (lane >> 3)) * 8);
  const __bf16* vSrc = Vh + (size_t)(lane >> 2) * S + ss * 1024 +
                       (((lane & 3) ^ ((lane >> 3) & 3)) * 8);

  // one wave stages BOTH K (4 chunks) and V (4 chunks) = 8 gload_lds / tile
  auto stage = [&](int it, int buf) {
    char* dst = smem + buf * 8192;
#pragma unroll
    for (int j = 0; j < 4; ++j)
      GLOAD_LDS16(kSrc + it * 2048 + j * 512, dst + j * 1024);
#pragma unroll
    for (int j = 0; j < 4; ++j)
      GLOAD_LDS16(vSrc + it * 32 + (size_t)j * 16 * S, dst + 4096 + j * 1024);
  };

  // hoisted Q fragments (issued first; FIFO-retired before tile waits)
  bf16x8 Qf[4];
#pragma unroll
  for (int kc = 0; kc < 4; ++kc)
    Qf[kc] = *reinterpret_cast<const bf16x8*>(
        &Qh[(size_t)(q0 + l31) * Dh + kc * 16 + hh * 8]);

  stage(0, 0);
  stage(1, 1);

  const f32x16 ZERO = {};
  f32x16 ot0 = {}, ot1 = {};   // Ot[d][q]: d 0-31 / 32-63

#pragma unroll 2
  for (int it = 0; it < 32; ++it) {
    const int buf = it & 1;
    // tile it's 8 staging loads are the oldest; keep tile it+1's in flight
    if (it + 1 < 32) {
      asm volatile("s_waitcnt vmcnt(8)" ::: "memory");
    } else {
      asm volatile("s_waitcnt vmcnt(0)" ::: "memory");
    }
    __builtin_amdgcn_sched_barrier(0);

    const __bf16* Kb = (const __bf16*)(smem + buf * 8192);
    const __bf16* Vb = (const __bf16*)(smem + buf * 8192 + 4096);

    // fragment reads
    bf16x8 kf[4], vf[4];
#pragma unroll
    for (int kc = 0; kc < 4; ++kc) {
      int x = (2 * kc + hh) ^ (l31 & 7);
      kf[kc] = *reinterpret_cast<const bf16x8*>(&Kb[l31 * 64 + x * 8]);
    }
#pragma unroll
    for (int kc2 = 0; kc2 < 2; ++kc2)
#pragma unroll
      for (int dblk = 0; dblk < 2; ++dblk) {
        int row = dblk * 32 + l31;
        int x   = (2 * kc2 + hh) ^ ((l31 >> 1) & 3);
        vf[kc2 * 2 + dblk] = *reinterpret_cast<const bf16x8*>(&Vb[row * 32 + x * 8]);
      }
    asm volatile("s_waitcnt lgkmcnt(0)" ::: "memory"); // reads retired
    __builtin_amdgcn_sched_barrier(0);

    if (it + 2 < 32) stage(it + 2, buf);   // refill freed buffer (no drain)

    // ---- St = K Q^T (swapped): lane holds S[s][q=l31] ----
    f32x16 sacc;
    __builtin_amdgcn_s_setprio(1);
    sacc = __builtin_amdgcn_mfma_f32_32x32x16_bf16(kf[0], Qf[0], ZERO, 0, 0, 0);
#pragma unroll
    for (int kc = 1; kc < 4; ++kc)
      sacc = __builtin_amdgcn_mfma_f32_32x32x16_bf16(kf[kc], Qf[kc], sacc, 0, 0, 0);
    __builtin_amdgcn_s_setprio(0);

    // ---- sigmoid in-register; F[kc2] = packed p[kc2*8 .. +7] ----
    bf16x8 F[2];
    {
      union { unsigned u[4]; bf16x8 v; } fu[2];
#pragma unroll
      for (int kc2 = 0; kc2 < 2; ++kc2) {
#pragma unroll
        for (int jj = 0; jj < 4; ++jj) {
          float ya = sacc[kc2 * 8 + 2 * jj];
          float yb = sacc[kc2 * 8 + 2 * jj + 1];
          float pa = __builtin_amdgcn_rcpf(1.0f + __builtin_amdgcn_exp2f(ya));
          float pb = __builtin_amdgcn_rcpf(1.0f + __builtin_amdgcn_exp2f(yb));
          fu[kc2].u[jj] = pk2(pa, pb);
        }
        F[kc2] = fu[kc2].v;
      }
    }

    // ---- Ot += Vt P (V s-cols pre-permuted -> F lane-local) ----
    __builtin_amdgcn_s_setprio(1);
    ot0 = __builtin_amdgcn_mfma_f32_32x32x16_bf16(vf[0], F[0], ot0, 0, 0, 0);
    ot1 = __builtin_amdgcn_mfma_f32_32x32x16_bf16(vf[1], F[0], ot1, 0, 0, 0);
    ot0 = __builtin_amdgcn_mfma_f32_32x32x16_bf16(vf[2], F[1], ot0, 0, 0, 0);
    ot1 = __builtin_amdgcn_mfma_f32_32x32x16_bf16(vf[3], F[1], ot1, 0, 0, 0);
    __builtin_amdgcn_s_setprio(0);
  }

  // ---- epilogue: transpose Ot via swizzled Os[32][128B], coalesced stores ----
  __syncthreads();   // 1 wave: drains counts before LDS reuse
  __bf16* Os = (__bf16*)smem;
  {
    int row = l31;
#pragma unroll
    for (int dblk = 0; dblk < 2; ++dblk)
#pragma unroll
      for (int rp = 0; rp < 4; ++rp) {
        int r  = rp * 4;
        int g  = dblk * 4 + rp;
        int by = row * 128 + ((g ^ (row & 7)) * 16) + hh * 8;
        float a0 = dblk ? ot1[r]     : ot0[r];
        float a1 = dblk ? ot1[r + 1] : ot0[r + 1];
        float a2 = dblk ? ot1[r + 2] : ot0[r + 2];
        float a3 = dblk ? ot1[r + 3] : ot0[r + 3];
        unsigned long long val =
            (unsigned long long)pk2(a0, a1) | ((unsigned long long)pk2(a2, a3) << 32);
        *reinterpret_cast<unsigned long long*>((char*)Os + by) = val;
      }
  }
  __syncthreads();
#pragma unroll
  for (int i = 0; i < 4; ++i) {
    int c   = i * 64 + t;              // 256 granules of 16B
    int row = c >> 3;
    int ch  = c & 7;
    bf16x8 v = *reinterpret_cast<const bf16x8*>(
        (char*)Os + row * 128 + ((ch ^ (row & 7)) * 16));
    *reinterpret_cast<bf16x8*>(
        &O[((size_t)(b * S) + q0 + row) * E2 + ss * 1024 + h * Dh + ch * 8]) = v;
  }
}

extern "C" void kernel_launch(void* const* d_in, const int* in_sizes, int n_in,
                              void* d_out, int out_size, void* d_ws, size_t ws_size,
                              hipStream_t stream) {
  const float* query = (const float*)d_in[0];
  const float* key_  = (const float*)d_in[1];
  const float* value = (const float*)d_in[2];
  const float* Wq    = (const float*)d_in[3];
  const float* Wk    = (const float*)d_in[4];
  const float* Wv    = (const float*)d_in[5];
  const float* Wo    = (const float*)d_in[6];

  char* ws = (char*)d_ws;
  __bf16* aq   = (__bf16*)(ws);                         // [M,E] bf16
  __bf16* ak   = (__bf16*)(ws + ((size_t)8 << 20));
  __bf16* av   = (__bf16*)(ws + ((size_t)16 << 20));
  __bf16* wqkv = (__bf16*)(ws + ((size_t)24 << 20));    // [3072,1024]
  __bf16* wob  = (__bf16*)(ws + ((size_t)30 << 20));    // [1024,1024]
  __bf16* pq   = (__bf16*)(ws + ((size_t)32 << 20));    // [B,H,S,D]
  __bf16* pk   = (__bf16*)(ws + ((size_t)40 << 20));    // [B,H,S,D]
  __bf16* pvt  = (__bf16*)(ws + ((size_t)48 << 20));    // [B,H,D,S] (s-perm)
  __bf16* ob   = (__bf16*)(ws);                         // [M,2048] aliases aq+ak

  convert_bf16<<<dim3(512, 7), 256, 0, stream>>>(query, key_, value, Wq, Wk, Wv,
                                                 Wo, aq, ak, av, wqkv, wob);

  // merged QKV projection: m97 structure, 768 blocks, XCD-chunked
  gemm_qkv<<<768, 256, 0, stream>>>(aq, ak, av, wqkv, pq, pk, pvt);

  // attention: 1-wave 32-q blocks x s-half -> 4096 blocks (4 waves/SIMD)
  attn_sigmoid<<<dim3(S / 16, H, Bsz), 64, 0, stream>>>(pq, pk, pvt, ob);

  // final GEMM: K=2048 concat of the two s-half partials vs wrapped Wo
  gemm_bf16nt<64, 2048><<<512, 256, 0, stream>>>(ob, wob, (float*)d_out);
}

// Round 17
// 130.695 us; speedup vs baseline: 1.1852x; 1.1852x over previous
//
#include <hip/hip_runtime.h>

typedef float f32x4 __attribute__((ext_vector_type(4)));
typedef float f32x16 __attribute__((ext_vector_type(16)));
typedef __bf16 bf16x4 __attribute__((ext_vector_type(4)));
typedef __bf16 bf16x8 __attribute__((ext_vector_type(8)));

constexpr int E = 1024;   // embed dim
constexpr int S = 2048;   // sequence length
constexpr int Bsz = 2;    // batch
constexpr int H = 16;     // heads
constexpr int Dh = 64;    // head dim
constexpr int M = Bsz * S; // 4096 rows
constexpr int E2 = 2048;  // ob row stride (two s-half partials, K-concat)

#define GLOAD_LDS16(g, l)                                                                 \
  __builtin_amdgcn_global_load_lds((const __attribute__((address_space(1))) void*)(g),    \
                                   (__attribute__((address_space(3))) void*)(l), 16, 0, 0)

__device__ __forceinline__ unsigned pk2(float a, float b) {
  union { __bf16 h[2]; unsigned u; } r;
  r.h[0] = (__bf16)a; r.h[1] = (__bf16)b;
  return r.u;
}

// ---------------------------------------------------------------------------
// fp32 -> bf16 convert pass (unchanged, verified).
// ---------------------------------------------------------------------------
__global__ __launch_bounds__(256) void convert_bf16(
    const float* __restrict__ q, const float* __restrict__ k,
    const float* __restrict__ v, const float* __restrict__ wq,
    const float* __restrict__ wk, const float* __restrict__ wv,
    const float* __restrict__ wo, __bf16* __restrict__ aq,
    __bf16* __restrict__ ak, __bf16* __restrict__ av,
    __bf16* __restrict__ wqkv, __bf16* __restrict__ wob) {
  const int id = blockIdx.y;
  const float* src;
  __bf16* dst;
  int n;
  float scale = 1.0f;
  switch (id) {
    case 0: src = q;  dst = aq;             n = M * E; break;
    case 1: src = k;  dst = ak;             n = M * E; break;
    case 2: src = v;  dst = av;             n = M * E; break;
    case 3: src = wq; dst = wqkv;           n = E * E; scale = -0.18033688f; break;
    case 4: src = wk; dst = wqkv + E * E;   n = E * E; break;
    case 5: src = wv; dst = wqkv + 2 * E * E; n = E * E; break;
    default: src = wo; dst = wob;           n = E * E; break;
  }
  const int stride = gridDim.x * 256 * 8;
  for (int i = (blockIdx.x * 256 + threadIdx.x) * 8; i < n; i += stride) {
    f32x4 a = *reinterpret_cast<const f32x4*>(&src[i]);
    f32x4 b = *reinterpret_cast<const f32x4*>(&src[i + 4]);
    bf16x8 o;
    o[0] = (__bf16)(a[0] * scale); o[1] = (__bf16)(a[1] * scale);
    o[2] = (__bf16)(a[2] * scale); o[3] = (__bf16)(a[3] * scale);
    o[4] = (__bf16)(b[0] * scale); o[5] = (__bf16)(b[1] * scale);
    o[6] = (__bf16)(b[2] * scale); o[7] = (__bf16)(b[3] * scale);
    *reinterpret_cast<bf16x8*>(&dst[i]) = o;
  }
}

// ---------------------------------------------------------------------------
// Merged QKV projection GEMM v5 (round-14 verified): exact m97 structure,
// 128x128 tile, BK=64, single 32 KB buffer, __syncthreads drain schedule,
// XCD-chunked m-major grid. pq/pk [B,H,S,D]; pvt [B,H,D,S] s bits-2<->3.
// ---------------------------------------------------------------------------
__global__ __launch_bounds__(256) void gemm_qkv(
    const __bf16* __restrict__ A0, const __bf16* __restrict__ A1,
    const __bf16* __restrict__ A2, const __bf16* __restrict__ Bw,
    __bf16* __restrict__ C0, __bf16* __restrict__ C1, __bf16* __restrict__ C2) {
  constexpr int NT  = 16;            // k-tiles of 64 (K=1024)
  constexpr int NTN = 24;            // 3072/128
  constexpr int NWG = 32 * NTN;      // 768
  constexpr int CPX = NWG / 8;       // 96

  __shared__ char smem[32768];       // A [128][64] 16KB | B [128][64] 16KB

  const int t    = threadIdx.x;
  const int lane = t & 63;
  const int wid  = t >> 6;
  const int wr   = (wid >> 1) * 64;
  const int wc   = (wid & 1) * 64;
  const int r16  = lane & 15;

  const int bid = blockIdx.x;
  const int fid = (bid & 7) * CPX + (bid >> 3);
  const int mt  = fid / NTN;
  const int nt  = fid % NTN;
  const int tm  = mt * 128;
  const int tn  = nt * 128;
  const int which = tn >> 10;

  const __bf16* Ab = which == 0 ? A0 : which == 1 ? A1 : A2;

  auto stage = [&](int kt) {
    const int k0 = kt * 64;
#pragma unroll
    for (int c = wid; c < 32; c += 4) {
      const bool isA = c < 16;
      const int cc   = isA ? c : c - 16;
      const int L    = cc * 1024 + lane * 16;   // byte offset in tile
      const int row  = L >> 7;                  // 128 B per row
      const int sw   = ((L >> 4) & 7) ^ (row & 7);
      const __bf16* src = isA ? &Ab[(size_t)(tm + row) * 1024 + k0 + sw * 8]
                              : &Bw[(size_t)(tn + row) * 1024 + k0 + sw * 8];
      GLOAD_LDS16(src, smem + c * 1024);
    }
  };

  f32x4 acc[4][4] = {};

  for (int kt = 0; kt < NT; ++kt) {
    __syncthreads();                 // prior tile's readers done
    stage(kt);
    __syncthreads();                 // full drain: tile kt staged

    const char* As = smem;
    const char* Bs = smem + 16384;

#pragma unroll
    for (int kc = 0; kc < 2; ++kc) {
      bf16x8 af[4], bfv[4];
#pragma unroll
      for (int mi = 0; mi < 4; ++mi) {
        int row = wr + mi * 16 + r16;
        int g   = (kc * 4 + (lane >> 4)) ^ (row & 7);
        af[mi] = *reinterpret_cast<const bf16x8*>(As + row * 128 + g * 16);
      }
#pragma unroll
      for (int ni = 0; ni < 4; ++ni) {
        int row = wc + ni * 16 + r16;
        int g   = (kc * 4 + (lane >> 4)) ^ (row & 7);
        bfv[ni] = *reinterpret_cast<const bf16x8*>(Bs + row * 128 + g * 16);
      }
      __builtin_amdgcn_s_setprio(1);
#pragma unroll
      for (int mi = 0; mi < 4; ++mi)
#pragma unroll
        for (int ni = 0; ni < 4; ++ni)
          acc[mi][ni] = __builtin_amdgcn_mfma_f32_16x16x32_bf16(af[mi], bfv[ni],
                                                                acc[mi][ni], 0, 0, 0);
      __builtin_amdgcn_s_setprio(0);
    }
  }

#pragma unroll
  for (int mi = 0; mi < 4; ++mi) {
#pragma unroll
    for (int ni = 0; ni < 4; ++ni) {
#pragma unroll
      for (int j = 0; j < 4; ++j) {
        float v = acc[mi][ni][j];
        int m = tm + wr + mi * 16 + ((lane >> 4) << 2) + j;
        int n = tn + wc + ni * 16 + r16;
        int nl = n & 1023;
        int b = m >> 11, s = m & 2047, h = nl >> 6, d = nl & 63;
        __bf16* Cout = which == 0 ? C0 : which == 1 ? C1 : C2;
        if (which < 2) {
          Cout[((size_t)(b * H + h) * S + s) * Dh + d] = (__bf16)v;
        } else {
          int ssw = (s & ~12) | ((s & 4) << 1) | ((s & 8) >> 1);
          Cout[((size_t)(b * H + h) * Dh + d) * S + ssw] = (__bf16)v;
        }
      }
    }
  }
}

// ---------------------------------------------------------------------------
// Final GEMM (round-7/9/14 verified): TM=64, counted-vmcnt dbuf, XCD-chunked
// grid. KS=2048 K-concat of the two s-half partials; B k-index wraps 1024.
// ---------------------------------------------------------------------------
template <int TM, int KS>
__global__ __launch_bounds__(256) void gemm_bf16nt(
    const __bf16* __restrict__ A0, const __bf16* __restrict__ Bw,
    float* __restrict__ C0) {
  static_assert(TM == 64, "vmcnt literal assumes TM=64 (6 chunks/wave)");
  constexpr int MI  = TM / 32;
  constexpr int NT  = KS / 64;
  constexpr int ACH = TM / 8;
  constexpr int NCH = ACH + 16;
  constexpr int NTN = 8;
  constexpr int NWG = NTN * (M / TM);
  constexpr int CPX = NWG / 8;

  __shared__ char smem[2][NCH * 1024];   // 48 KB total

  const int t    = threadIdx.x;
  const int lane = t & 63;
  const int wid  = t >> 6;
  const int wr   = (wid >> 1) * (TM / 2);
  const int wc   = (wid & 1) * 64;
  const int r16  = lane & 15;

  const int bid = blockIdx.x;
  const int fid = (bid & 7) * CPX + (bid >> 3);
  const int mt  = fid / NTN;
  const int nt  = fid % NTN;
  const int tm  = mt * TM;
  const int tn  = nt * 128;

  auto stage = [&](int kt, int buf) {
    const int k0  = kt * 64;
    const int k0b = k0 & 1023;
    char* dst = smem[buf];
#pragma unroll
    for (int c = wid; c < NCH; c += 4) {
      const bool isA = c < ACH;
      const int cc   = isA ? c : c - ACH;
      const int L    = cc * 1024 + lane * 16;
      const int row  = L >> 7;
      const int sw   = ((L >> 4) & 7) ^ (row & 7);
      const __bf16* src = isA ? &A0[(size_t)(tm + row) * KS + k0 + sw * 8]
                              : &Bw[(size_t)(tn + row) * 1024 + k0b + sw * 8];
      GLOAD_LDS16(src, dst + c * 1024);
    }
  };

  stage(0, 0);
  stage(1, 1);

  f32x4 acc[MI][4] = {};

  for (int kt = 0; kt < NT; ++kt) {
    const int buf = kt & 1;
    if (kt + 1 < NT) {
      asm volatile("s_waitcnt vmcnt(6)" ::: "memory");
    } else {
      asm volatile("s_waitcnt vmcnt(0)" ::: "memory");
    }
    __builtin_amdgcn_s_barrier();
    __builtin_amdgcn_sched_barrier(0);

    const __bf16* As = (const __bf16*)smem[buf];
    const __bf16* Bs = (const __bf16*)(smem[buf] + ACH * 1024);

#pragma unroll
    for (int kc = 0; kc < 2; ++kc) {
      bf16x8 af[MI], bfv[4];
#pragma unroll
      for (int mi = 0; mi < MI; ++mi) {
        int row = wr + mi * 16 + r16;
        int g   = (kc * 4 + (lane >> 4)) ^ (row & 7);
        af[mi] = *reinterpret_cast<const bf16x8*>(&As[row * 64 + g * 8]);
      }
#pragma unroll
      for (int ni = 0; ni < 4; ++ni) {
        int row = wc + ni * 16 + r16;
        int g   = (kc * 4 + (lane >> 4)) ^ (row & 7);
        bfv[ni] = *reinterpret_cast<const bf16x8*>(&Bs[row * 64 + g * 8]);
      }
      __builtin_amdgcn_s_setprio(1);
#pragma unroll
      for (int mi = 0; mi < MI; ++mi)
#pragma unroll
        for (int ni = 0; ni < 4; ++ni)
          acc[mi][ni] = __builtin_amdgcn_mfma_f32_16x16x32_bf16(af[mi], bfv[ni],
                                                                acc[mi][ni], 0, 0, 0);
      __builtin_amdgcn_s_setprio(0);
    }

    __builtin_amdgcn_sched_barrier(0);
    __builtin_amdgcn_s_barrier();
    if (kt + 2 < NT) stage(kt + 2, buf);
  }

#pragma unroll
  for (int mi = 0; mi < MI; ++mi) {
#pragma unroll
    for (int ni = 0; ni < 4; ++ni) {
#pragma unroll
      for (int j = 0; j < 4; ++j) {
        float v = acc[mi][ni][j];
        int m = tm + wr + mi * 16 + ((lane >> 4) << 2) + j;
        int n = tn + wc + ni * 16 + r16;
        C0[(size_t)m * E + n] = v;
      }
    }
  }
}

// ---------------------------------------------------------------------------
// Sigmoid attention v9 (round-9/14 verified pipeline, byte-identical) +
// XCD-chunked 1-D grid: blocks on the same XCD share (b,h) -> K/V working
// set per XCD = 2 MB <= 4 MB L2 -> staging loads L2-hit -> shorter vmcnt
// waits. fid = ((b*H+h)*64) + x, x = qt*2+ss; XCD chunk = 256 fids.
// ---------------------------------------------------------------------------
__global__ __launch_bounds__(64, 2) void attn_sigmoid(const __bf16* __restrict__ Q,
                                                      const __bf16* __restrict__ K,
                                                      const __bf16* __restrict__ Vt,
                                                      __bf16* __restrict__ O) {
  __shared__ char smem[16384];   // [buf]: K tile 4KB (32s x 64d) + V tile 4KB

  const int t    = threadIdx.x;
  const int lane = t & 63;
  const int l31  = lane & 31;
  const int hh   = lane >> 5;

  // bijective XCD-chunk swizzle (2048 blocks, 256 per XCD)
  const int bid = blockIdx.x;
  const int fid = (bid & 7) * 256 + (bid >> 3);
  const int x   = fid & 63;          // 64 x-blocks per (b,h)
  const int bh  = fid >> 6;          // 0..31
  const int h   = bh & 15;
  const int b   = bh >> 4;
  const int qt  = x >> 1;
  const int ss  = x & 1;
  const int q0  = qt * 64;

  const __bf16* Qh = Q + (size_t)(b * H + h) * S * Dh;
  const __bf16* Kh = K + (size_t)(b * H + h) * S * Dh;
  const __bf16* Vh = Vt + (size_t)(b * H + h) * Dh * S;

  const __bf16* kSrc = Kh + (size_t)(ss * 1024 + (lane >> 3)) * Dh +
                       (((lane & 7) ^ (lane >> 3)) * 8);
  const __bf16* vSrc = Vh + (size_t)(lane >> 2) * S + ss * 1024 +
                       (((lane & 3) ^ ((lane >> 3) & 3)) * 8);

  auto stage = [&](int it, int buf) {
    char* dst = smem + buf * 8192;
#pragma unroll
    for (int j = 0; j < 4; ++j)
      GLOAD_LDS16(kSrc + it * 2048 + j * 512, dst + j * 1024);
#pragma unroll
    for (int j = 0; j < 4; ++j)
      GLOAD_LDS16(vSrc + it * 32 + (size_t)j * 16 * S, dst + 4096 + j * 1024);
  };

  bf16x8 Qf[2][4];
#pragma unroll
  for (int g = 0; g < 2; ++g)
#pragma unroll
    for (int kc = 0; kc < 4; ++kc)
      Qf[g][kc] = *reinterpret_cast<const bf16x8*>(
          &Qh[(size_t)(q0 + g * 32 + l31) * Dh + kc * 16 + hh * 8]);

  stage(0, 0);
  stage(1, 1);

  const f32x16 ZERO = {};
  f32x16 ot[2][2] = {};   // [g][dblk]

#pragma unroll 2
  for (int it = 0; it < 32; ++it) {
    const int buf = it & 1;
    if (it + 1 < 32) {
      asm volatile("s_waitcnt vmcnt(8)" ::: "memory");
    } else {
      asm volatile("s_waitcnt vmcnt(0)" ::: "memory");
    }
    __builtin_amdgcn_sched_barrier(0);

    const __bf16* Kb = (const __bf16*)(smem + buf * 8192);
    const __bf16* Vb = (const __bf16*)(smem + buf * 8192 + 4096);

    bf16x8 kf[4], vf[4];
#pragma unroll
    for (int kc = 0; kc < 4; ++kc) {
      int xg = (2 * kc + hh) ^ (l31 & 7);
      kf[kc] = *reinterpret_cast<const bf16x8*>(&Kb[l31 * 64 + xg * 8]);
    }
#pragma unroll
    for (int kc2 = 0; kc2 < 2; ++kc2)
#pragma unroll
      for (int dblk = 0; dblk < 2; ++dblk) {
        int row = dblk * 32 + l31;
        int xg  = (2 * kc2 + hh) ^ ((l31 >> 1) & 3);
        vf[kc2 * 2 + dblk] = *reinterpret_cast<const bf16x8*>(&Vb[row * 32 + xg * 8]);
      }
    asm volatile("s_waitcnt lgkmcnt(0)" ::: "memory");
    __builtin_amdgcn_sched_barrier(0);

    if (it + 2 < 32) stage(it + 2, buf);

    f32x16 s0, s1;
    __builtin_amdgcn_s_setprio(1);
    s0 = __builtin_amdgcn_mfma_f32_32x32x16_bf16(kf[0], Qf[0][0], ZERO, 0, 0, 0);
    s1 = __builtin_amdgcn_mfma_f32_32x32x16_bf16(kf[0], Qf[1][0], ZERO, 0, 0, 0);
#pragma unroll
    for (int kc = 1; kc < 4; ++kc) {
      s0 = __builtin_amdgcn_mfma_f32_32x32x16_bf16(kf[kc], Qf[0][kc], s0, 0, 0, 0);
      s1 = __builtin_amdgcn_mfma_f32_32x32x16_bf16(kf[kc], Qf[1][kc], s1, 0, 0, 0);
    }
    __builtin_amdgcn_s_setprio(0);

    bf16x8 F[2][2];
#pragma unroll
    for (int g = 0; g < 2; ++g) {
      union { unsigned u[4]; bf16x8 v; } fu[2];
#pragma unroll
      for (int kc2 = 0; kc2 < 2; ++kc2) {
#pragma unroll
        for (int jj = 0; jj < 4; ++jj) {
          float ya = g ? s1[kc2 * 8 + 2 * jj] : s0[kc2 * 8 + 2 * jj];
          float yb = g ? s1[kc2 * 8 + 2 * jj + 1] : s0[kc2 * 8 + 2 * jj + 1];
          float pa = __builtin_amdgcn_rcpf(1.0f + __builtin_amdgcn_exp2f(ya));
          float pb = __builtin_amdgcn_rcpf(1.0f + __builtin_amdgcn_exp2f(yb));
          fu[kc2].u[jj] = pk2(pa, pb);
        }
        F[g][kc2] = fu[kc2].v;
      }
    }

    __builtin_amdgcn_s_setprio(1);
#pragma unroll
    for (int kc2 = 0; kc2 < 2; ++kc2) {
#pragma unroll
      for (int dblk = 0; dblk < 2; ++dblk) {
        ot[0][dblk] = __builtin_amdgcn_mfma_f32_32x32x16_bf16(
            vf[kc2 * 2 + dblk], F[0][kc2], ot[0][dblk], 0, 0, 0);
        ot[1][dblk] = __builtin_amdgcn_mfma_f32_32x32x16_bf16(
            vf[kc2 * 2 + dblk], F[1][kc2], ot[1][dblk], 0, 0, 0);
      }
    }
    __builtin_amdgcn_s_setprio(0);
  }

  __syncthreads();
  __bf16* Os = (__bf16*)smem;
#pragma unroll
  for (int g = 0; g < 2; ++g) {
    int row = g * 32 + l31;
#pragma unroll
    for (int dblk = 0; dblk < 2; ++dblk)
#pragma unroll
      for (int rp = 0; rp < 4; ++rp) {
        int r  = rp * 4;
        int gg = dblk * 4 + rp;
        int by = row * 128 + ((gg ^ (row & 7)) * 16) + hh * 8;
        float a0 = ot[g][dblk][r];
        float a1 = ot[g][dblk][r + 1];
        float a2 = ot[g][dblk][r + 2];
        float a3 = ot[g][dblk][r + 3];
        unsigned long long val =
            (unsigned long long)pk2(a0, a1) | ((unsigned long long)pk2(a2, a3) << 32);
        *reinterpret_cast<unsigned long long*>((char*)Os + by) = val;
      }
  }
  __syncthreads();
#pragma unroll
  for (int i = 0; i < 8; ++i) {
    int c   = i * 64 + t;              // 512 granules of 16B
    int row = c >> 3;
    int ch  = c & 7;
    bf16x8 v = *reinterpret_cast<const bf16x8*>(
        (char*)Os + row * 128 + ((ch ^ (row & 7)) * 16));
    *reinterpret_cast<bf16x8*>(
        &O[((size_t)(b * S) + q0 + row) * E2 + ss * 1024 + h * Dh + ch * 8]) = v;
  }
}

extern "C" void kernel_launch(void* const* d_in, const int* in_sizes, int n_in,
                              void* d_out, int out_size, void* d_ws, size_t ws_size,
                              hipStream_t stream) {
  const float* query = (const float*)d_in[0];
  const float* key_  = (const float*)d_in[1];
  const float* value = (const float*)d_in[2];
  const float* Wq    = (const float*)d_in[3];
  const float* Wk    = (const float*)d_in[4];
  const float* Wv    = (const float*)d_in[5];
  const float* Wo    = (const float*)d_in[6];

  char* ws = (char*)d_ws;
  __bf16* aq   = (__bf16*)(ws);                         // [M,E] bf16
  __bf16* ak   = (__bf16*)(ws + ((size_t)8 << 20));
  __bf16* av   = (__bf16*)(ws + ((size_t)16 << 20));
  __bf16* wqkv = (__bf16*)(ws + ((size_t)24 << 20));    // [3072,1024]
  __bf16* wob  = (__bf16*)(ws + ((size_t)30 << 20));    // [1024,1024]
  __bf16* pq   = (__bf16*)(ws + ((size_t)32 << 20));    // [B,H,S,D]
  __bf16* pk   = (__bf16*)(ws + ((size_t)40 << 20));    // [B,H,S,D]
  __bf16* pvt  = (__bf16*)(ws + ((size_t)48 << 20));    // [B,H,D,S] (s-perm)
  __bf16* ob   = (__bf16*)(ws);                         // [M,2048] aliases aq+ak

  convert_bf16<<<dim3(512, 7), 256, 0, stream>>>(query, key_, value, Wq, Wk, Wv,
                                                 Wo, aq, ak, av, wqkv, wob);

  // merged QKV projection: m97 structure, 768 blocks, XCD-chunked
  gemm_qkv<<<768, 256, 0, stream>>>(aq, ak, av, wqkv, pq, pk, pvt);

  // attention: v9 pipeline, 2048 1-D blocks with XCD-chunked (b,h) locality
  attn_sigmoid<<<2048, 64, 0, stream>>>(pq, pk, pvt, ob);

  // final GEMM: K=2048 concat of the two s-half partials vs wrapped Wo
  gemm_bf16nt<64, 2048><<<512, 256, 0, stream>>>(ob, wob, (float*)d_out);
}